// Round 6
// baseline (322.240 us; speedup 1.0000x reference)
//
#include <hip/hip_runtime.h>

// GraphSAGE 2-layer pipeline, fp16 activations + MFMA f16 (weights hi+lo 2-term).
// Layer-1 linear_pre is algebraically fused into conv_first's two GEMMs:
//   t1 = x@(Wpre@Wl1) + b_pre@Wl1,  r1 = x@(Wpre@Wr1) + b_pre@Wr1
// (valid because there is no nonlinearity between linear_pre and conv_first,
//  and mean-aggregation commutes with right-multiplication; deg=0 -> aggr=0 in
//  both formulations).
// N=50000, E=600000, edge_index int32.

#define NN   50000
#define EE   600000
#define NBLK 49          // ceil(NN/1024)
#define NRG  1563        // ceil(NN/32) row-groups of 32 rows
#define GEMM_BLOCKS 512

typedef __attribute__((ext_vector_type(8))) _Float16 h8v;
typedef __attribute__((ext_vector_type(4))) _Float16 h4v;
typedef __attribute__((ext_vector_type(2))) _Float16 h2v;
typedef __attribute__((ext_vector_type(8))) short short8v;
typedef __attribute__((ext_vector_type(4))) float f32x4;

__device__ inline h8v h8zero() {
    return __builtin_bit_cast(h8v, (short8v){0,0,0,0,0,0,0,0});
}

__device__ inline h8v cvt8(const float* __restrict__ p) {
    float4 f0 = *(const float4*)p;
    float4 f1 = *(const float4*)(p + 4);
    h8v a;
    a[0] = (_Float16)f0.x; a[1] = (_Float16)f0.y;
    a[2] = (_Float16)f0.z; a[3] = (_Float16)f0.w;
    a[4] = (_Float16)f1.x; a[5] = (_Float16)f1.y;
    a[6] = (_Float16)f1.z; a[7] = (_Float16)f1.w;
    return a;
}

// ---------------- CSR build ----------------

__global__ __launch_bounds__(256) void k_count(const int* __restrict__ ei,
                                               int* __restrict__ counts) {
    int e = blockIdx.x * 256 + threadIdx.x;
    if (e < EE) atomicAdd(&counts[ei[EE + e]], 1);
}

__global__ __launch_bounds__(256) void k_scan_a(const int* __restrict__ counts,
                                                int* __restrict__ bsums) {
    int b = blockIdx.x, t = threadIdx.x;
    int idx = b * 1024 + t * 4;
    int s = 0;
#pragma unroll
    for (int j = 0; j < 4; ++j)
        if (idx + j < NN) s += counts[idx + j];
#pragma unroll
    for (int off = 32; off > 0; off >>= 1) s += __shfl_down(s, off);
    __shared__ int ls[4];
    if ((t & 63) == 0) ls[t >> 6] = s;
    __syncthreads();
    if (t == 0) bsums[b] = ls[0] + ls[1] + ls[2] + ls[3];
}

__global__ void k_scan_b(int* __restrict__ bsums) {
    int t = threadIdx.x;                       // 64 threads
    int v = (t < NBLK) ? bsums[t] : 0;
    int orig = v;
#pragma unroll
    for (int off = 1; off < 64; off <<= 1) {
        int u = __shfl_up(v, off);
        if (t >= off) v += u;
    }
    if (t < NBLK) bsums[t] = v - orig;          // exclusive
}

__global__ __launch_bounds__(256) void k_scan_c(const int* __restrict__ counts,
                                                const int* __restrict__ bsums,
                                                int* __restrict__ rowp) {
    int b = blockIdx.x, t = threadIdx.x;
    int lane = t & 63, wave = t >> 6;
    int idx = b * 1024 + t * 4;
    int c[4], s = 0;
#pragma unroll
    for (int j = 0; j < 4; ++j) {
        c[j] = (idx + j < NN) ? counts[idx + j] : 0;
        s += c[j];
    }
    int sv = s;
#pragma unroll
    for (int off = 1; off < 64; off <<= 1) {
        int u = __shfl_up(sv, off);
        if (lane >= off) sv += u;
    }
    __shared__ int lsum[4];
    if (lane == 63) lsum[wave] = sv;
    __syncthreads();
    int woff = 0;
    for (int wv = 0; wv < wave; ++wv) woff += lsum[wv];
    int base = bsums[b] + woff + (sv - s);
#pragma unroll
    for (int j = 0; j < 4; ++j) {
        if (idx + j < NN) { rowp[idx + j] = base; base += c[j]; }
    }
}

__global__ __launch_bounds__(256) void k_scatter(const int* __restrict__ ei,
                                                 const int* __restrict__ rowp,
                                                 int* __restrict__ cursor,
                                                 int* __restrict__ col) {
    int e = blockIdx.x * 256 + threadIdx.x;
    if (e < EE) {
        int d = ei[EE + e];
        int p = atomicAdd(&cursor[d], 1);
        col[rowp[d] + p] = ei[e];
    }
}

// ---- fused layer-1 weights: WA = Wpre@Wl1, WB = Wpre@Wr1 (fp32 dot, packed
// ---- transposed hi/lo fp16); bias rows bA = b_pre@Wl1, bB = b_pre@Wr1 (fp32).

__global__ __launch_bounds__(256) void k_fuse(const float* __restrict__ Wpre,
                                              const float* __restrict__ bpre,
                                              const float* __restrict__ Wl1,
                                              const float* __restrict__ Wr1,
                                              _Float16* __restrict__ WAH,
                                              _Float16* __restrict__ WAL,
                                              _Float16* __restrict__ WBH,
                                              _Float16* __restrict__ WBL,
                                              float* __restrict__ bA,
                                              float* __restrict__ bB) {
    int idx = blockIdx.x * 256 + threadIdx.x;     // 2*257*128 = 65792 exact
    int which = idx / (257 * 128);
    int rem = idx - which * 257 * 128;
    int i = rem >> 7, j = rem & 127;
    const float* W = which ? Wr1 : Wl1;
    float s = 0.f;
    if (i < 256) {
#pragma unroll 4
        for (int k = 0; k < 128; ++k) s += Wpre[i * 128 + k] * W[k * 128 + j];
        _Float16 h = (_Float16)s;
        _Float16 l = (_Float16)(s - (float)h);
        if (which) { WBH[j * 256 + i] = h; WBL[j * 256 + i] = l; }
        else       { WAH[j * 256 + i] = h; WAL[j * 256 + i] = l; }
    } else {
#pragma unroll 4
        for (int k = 0; k < 128; ++k) s += bpre[k] * W[k * 128 + j];
        if (which) bB[j] = s; else bA[j] = s;
    }
}

// ---- layer-2 weight pack: W[128][64] fp32 -> transposed [64][128] hi/lo fp16

__global__ __launch_bounds__(256) void k_pack2(const float* __restrict__ Wl2,
                                               const float* __restrict__ Wr2,
                                               _Float16* __restrict__ W2lH,
                                               _Float16* __restrict__ W2lL,
                                               _Float16* __restrict__ W2rH,
                                               _Float16* __restrict__ W2rL) {
    int idx = blockIdx.x * 256 + threadIdx.x;     // 2*8192 = 16384 exact
    int which = idx >> 13;
    int rem = idx & 8191;
    int k = rem >> 6, m = rem & 63;
    float w = (which ? Wr2 : Wl2)[rem];
    _Float16 h = (_Float16)w;
    _Float16 l = (_Float16)(w - (float)h);
    if (which) { W2rH[m * 128 + k] = h; W2rL[m * 128 + k] = l; }
    else       { W2lH[m * 128 + k] = h; W2lL[m * 128 + k] = l; }
}

// ---- fused dual GEMM: t1 = x@WA + bA, r1 = x@WB + bB  (K=256, M=128) --------
// Wave owns 16 cols; B (4 weight sets) in registers; A = fp32 x, cvt in-reg.

__global__ __launch_bounds__(256, 2) void k_gemm_fused(
        const float* __restrict__ x,
        const _Float16* __restrict__ WAH, const _Float16* __restrict__ WAL,
        const _Float16* __restrict__ WBH, const _Float16* __restrict__ WBL,
        const float* __restrict__ bA, const float* __restrict__ bB,
        _Float16* __restrict__ t1, _Float16* __restrict__ r1) {
    const int wave = threadIdx.x >> 6, lane = threadIdx.x & 63;
    const int r = lane & 15, kb = lane >> 4;
    const int gw = blockIdx.x * 4 + wave;
    const int col = ((gw & 7) << 4) + r;          // 8 col-slices of 16

    h8v wah[8], wal[8], wbh[8], wbl[8];
#pragma unroll
    for (int k = 0; k < 8; ++k) {
        size_t off = (size_t)col * 256 + k * 32 + kb * 8;
        wah[k] = *(const h8v*)&WAH[off];
        wal[k] = *(const h8v*)&WAL[off];
        wbh[k] = *(const h8v*)&WBH[off];
        wbl[k] = *(const h8v*)&WBL[off];
    }
    const float biasA = bA[col], biasB = bB[col];

    for (int rg = gw >> 3; rg < NRG; rg += (GEMM_BLOCKS * 4) / 8) {
        const int row0 = rg << 5;
        f32x4 accT[2], accR[2];
#pragma unroll
        for (int a = 0; a < 2; ++a) {
            accT[a] = (f32x4){0.f, 0.f, 0.f, 0.f};
            accR[a] = (f32x4){0.f, 0.f, 0.f, 0.f};
        }
#pragma unroll
        for (int k = 0; k < 8; ++k) {
#pragma unroll
            for (int rt = 0; rt < 2; ++rt) {
                int rr = row0 + rt * 16;          // tile-uniform validity
                h8v a = (rr < NN)
                    ? cvt8(&x[(size_t)(rr + r) * 256 + k * 32 + kb * 8])
                    : h8zero();
                accT[rt] = __builtin_amdgcn_mfma_f32_16x16x32_f16(a, wah[k], accT[rt], 0, 0, 0);
                accT[rt] = __builtin_amdgcn_mfma_f32_16x16x32_f16(a, wal[k], accT[rt], 0, 0, 0);
                accR[rt] = __builtin_amdgcn_mfma_f32_16x16x32_f16(a, wbh[k], accR[rt], 0, 0, 0);
                accR[rt] = __builtin_amdgcn_mfma_f32_16x16x32_f16(a, wbl[k], accR[rt], 0, 0, 0);
            }
        }
#pragma unroll
        for (int rt = 0; rt < 2; ++rt) {
            if (row0 + rt * 16 >= NN) continue;
            int rbase = row0 + rt * 16 + kb * 4;  // C: row=4*(lane>>4)+reg
#pragma unroll
            for (int j = 0; j < 4; ++j) {
                t1[(size_t)(rbase + j) * 128 + col] = (_Float16)(accT[rt][j] + biasA);
                r1[(size_t)(rbase + j) * 128 + col] = (_Float16)(accR[rt][j] + biasB);
            }
        }
    }
}

// ------- Dual GEMM: T = A@W1, R = A@W2 (K=128, M=64), fp16 out ----------------

template <int M>
__global__ __launch_bounds__(256, 2) void k_gemm_dual(
        const _Float16* __restrict__ A,
        const _Float16* __restrict__ W1H, const _Float16* __restrict__ W1L,
        const _Float16* __restrict__ W2H, const _Float16* __restrict__ W2L,
        _Float16* __restrict__ T, _Float16* __restrict__ R) {
    constexpr int CS = M / 32;
    const int wave = threadIdx.x >> 6, lane = threadIdx.x & 63;
    const int r = lane & 15, kb = lane >> 4;
    const int gw = blockIdx.x * 4 + wave;
    const int col0 = (gw % CS) << 5;

    h8v b1h[2][4], b1l[2][4], b2h[2][4], b2l[2][4];
#pragma unroll
    for (int nt = 0; nt < 2; ++nt)
#pragma unroll
        for (int k = 0; k < 4; ++k) {
            size_t off = (size_t)(col0 + nt * 16 + r) * 128 + k * 32 + kb * 8;
            b1h[nt][k] = *(const h8v*)&W1H[off];
            b1l[nt][k] = *(const h8v*)&W1L[off];
            b2h[nt][k] = *(const h8v*)&W2H[off];
            b2l[nt][k] = *(const h8v*)&W2L[off];
        }

    const int stride = (GEMM_BLOCKS * 4) / CS;
    for (int rg = gw / CS; rg < NRG; rg += stride) {
        const int row0 = rg << 5;
        f32x4 accT[2][2], accR[2][2];
#pragma unroll
        for (int a = 0; a < 2; ++a)
#pragma unroll
            for (int b = 0; b < 2; ++b) {
                accT[a][b] = (f32x4){0.f, 0.f, 0.f, 0.f};
                accR[a][b] = (f32x4){0.f, 0.f, 0.f, 0.f};
            }
#pragma unroll
        for (int k = 0; k < 4; ++k) {
            h8v ah[2];
#pragma unroll
            for (int rt = 0; rt < 2; ++rt) {
                int rr = row0 + rt * 16;
                ah[rt] = (rr < NN) ? *(const h8v*)&A[(size_t)(rr + r) * 128 + k * 32 + kb * 8]
                                   : h8zero();
            }
#pragma unroll
            for (int rt = 0; rt < 2; ++rt)
#pragma unroll
                for (int nt = 0; nt < 2; ++nt) {
                    accT[rt][nt] = __builtin_amdgcn_mfma_f32_16x16x32_f16(ah[rt], b1h[nt][k], accT[rt][nt], 0, 0, 0);
                    accT[rt][nt] = __builtin_amdgcn_mfma_f32_16x16x32_f16(ah[rt], b1l[nt][k], accT[rt][nt], 0, 0, 0);
                    accR[rt][nt] = __builtin_amdgcn_mfma_f32_16x16x32_f16(ah[rt], b2h[nt][k], accR[rt][nt], 0, 0, 0);
                    accR[rt][nt] = __builtin_amdgcn_mfma_f32_16x16x32_f16(ah[rt], b2l[nt][k], accR[rt][nt], 0, 0, 0);
                }
        }
#pragma unroll
        for (int rt = 0; rt < 2; ++rt) {
            if (row0 + rt * 16 >= NN) continue;
            int rbase = row0 + rt * 16 + kb * 4;
#pragma unroll
            for (int nt = 0; nt < 2; ++nt) {
                int c = col0 + nt * 16 + r;
#pragma unroll
                for (int j = 0; j < 4; ++j) {
                    T[(size_t)(rbase + j) * M + c] = (_Float16)accT[rt][nt][j];
                    R[(size_t)(rbase + j) * M + c] = (_Float16)accR[rt][nt][j];
                }
            }
        }
    }
}

// ------- Aggregation 1: h1 = fp16(relu(mean(t1[src]) + bl1 + r1)) -------------
// one wave per node; two 32-lane halves, h4v (8B) loads, 2 neighbors/step.

__global__ __launch_bounds__(256) void k_aggr1(const _Float16* __restrict__ t1,
                                               const _Float16* __restrict__ r1,
                                               const int* __restrict__ rowp,
                                               const int* __restrict__ counts,
                                               const int* __restrict__ col,
                                               const float* __restrict__ bl1,
                                               _Float16* __restrict__ h1) {
    int node = blockIdx.x * 4 + (threadIdx.x >> 6);
    int lane = threadIdx.x & 63;
    if (node >= NN) return;
    int half = lane >> 5, sl = lane & 31;
    int e0 = rowp[node], cnt = counts[node];
    float a0 = 0.f, a1 = 0.f, a2 = 0.f, a3 = 0.f;
    const h4v* T = (const h4v*)t1;                 // 32 h4v per row
    for (int base = 0; base < cnt; base += 64) {
        int m = cnt - base; if (m > 64) m = 64;
        int myS = (base + lane < cnt) ? col[e0 + base + lane] : 0;
        int i = 0;
        for (; i + 8 <= m; i += 8) {
            int s0 = __shfl(myS, i + 0 + half), s1 = __shfl(myS, i + 2 + half);
            int s2 = __shfl(myS, i + 4 + half), s3 = __shfl(myS, i + 6 + half);
            h4v v0 = T[(size_t)s0 * 32 + sl], v1 = T[(size_t)s1 * 32 + sl];
            h4v v2 = T[(size_t)s2 * 32 + sl], v3 = T[(size_t)s3 * 32 + sl];
            a0 += (float)v0[0] + (float)v1[0] + (float)v2[0] + (float)v3[0];
            a1 += (float)v0[1] + (float)v1[1] + (float)v2[1] + (float)v3[1];
            a2 += (float)v0[2] + (float)v1[2] + (float)v2[2] + (float)v3[2];
            a3 += (float)v0[3] + (float)v1[3] + (float)v2[3] + (float)v3[3];
        }
        for (; i < m; i += 2) {
            if (i + half < m) {
                int s = __shfl(myS, i + half);
                h4v v = T[(size_t)s * 32 + sl];
                a0 += (float)v[0]; a1 += (float)v[1];
                a2 += (float)v[2]; a3 += (float)v[3];
            }
        }
    }
    a0 += __shfl_xor(a0, 32); a1 += __shfl_xor(a1, 32);
    a2 += __shfl_xor(a2, 32); a3 += __shfl_xor(a3, 32);
    float di = (cnt > 0) ? 1.0f / (float)cnt : 0.0f;
    h4v rr = ((const h4v*)r1)[(size_t)node * 32 + sl];
    float4 bb = ((const float4*)bl1)[sl];
    if (half == 0) {
        h4v h;
        h[0] = (_Float16)fmaxf(fmaf(a0, di, bb.x + (float)rr[0]), 0.0f);
        h[1] = (_Float16)fmaxf(fmaf(a1, di, bb.y + (float)rr[1]), 0.0f);
        h[2] = (_Float16)fmaxf(fmaf(a2, di, bb.z + (float)rr[2]), 0.0f);
        h[3] = (_Float16)fmaxf(fmaf(a3, di, bb.w + (float)rr[3]), 0.0f);
        ((h4v*)h1)[(size_t)node * 32 + sl] = h;
    }
}

// ------- Aggregation 2 + L2 normalize -----------------------------------------
// one wave per node; two 32-lane halves process 2 neighbors per step.

__global__ __launch_bounds__(256) void k_aggr2(const _Float16* __restrict__ t2,
                                               const _Float16* __restrict__ r2,
                                               const int* __restrict__ rowp,
                                               const int* __restrict__ counts,
                                               const int* __restrict__ col,
                                               const float* __restrict__ bl2,
                                               float* __restrict__ out) {
    int node = blockIdx.x * 4 + (threadIdx.x >> 6);
    int lane = threadIdx.x & 63;
    if (node >= NN) return;
    int half = lane >> 5, sl = lane & 31;
    int e0 = rowp[node], cnt = counts[node];
    float ax = 0.f, ay = 0.f;
    const h2v* T = (const h2v*)t2;
    for (int base = 0; base < cnt; base += 64) {
        int m = cnt - base; if (m > 64) m = 64;
        int myS = (base + lane < cnt) ? col[e0 + base + lane] : 0;
        int i = 0;
        for (; i + 8 <= m; i += 8) {
            int s0 = __shfl(myS, i + 0 + half), s1 = __shfl(myS, i + 2 + half);
            int s2 = __shfl(myS, i + 4 + half), s3 = __shfl(myS, i + 6 + half);
            h2v v0 = T[(size_t)s0 * 32 + sl], v1 = T[(size_t)s1 * 32 + sl];
            h2v v2 = T[(size_t)s2 * 32 + sl], v3 = T[(size_t)s3 * 32 + sl];
            ax += (float)v0[0] + (float)v1[0] + (float)v2[0] + (float)v3[0];
            ay += (float)v0[1] + (float)v1[1] + (float)v2[1] + (float)v3[1];
        }
        for (; i < m; i += 2) {
            if (i + half < m) {
                int s = __shfl(myS, i + half);
                h2v v = T[(size_t)s * 32 + sl];
                ax += (float)v[0]; ay += (float)v[1];
            }
        }
    }
    ax += __shfl_xor(ax, 32);
    ay += __shfl_xor(ay, 32);
    float di = (cnt > 0) ? 1.0f / (float)cnt : 0.0f;
    h2v rr = ((const h2v*)r2)[(size_t)node * 32 + sl];
    float2 bb = ((const float2*)bl2)[sl];
    float v0 = fmaf(ax, di, bb.x + (float)rr[0]);
    float v1 = fmaf(ay, di, bb.y + (float)rr[1]);
    float ss = v0 * v0 + v1 * v1;
#pragma unroll
    for (int off = 16; off > 0; off >>= 1) ss += __shfl_xor(ss, off);
    float inv = 1.0f / fmaxf(sqrtf(ss), 1e-12f);
    if (half == 0)
        ((float2*)out)[(size_t)node * 32 + sl] = make_float2(v0 * inv, v1 * inv);
}

// ---------------- launch ----------------

extern "C" void kernel_launch(void* const* d_in, const int* in_sizes, int n_in,
                              void* d_out, int out_size, void* d_ws, size_t ws_size,
                              hipStream_t stream) {
    const float* x    = (const float*)d_in[0];
    const int*   ei   = (const int*)d_in[1];
    const float* Wpre = (const float*)d_in[2];
    const float* bpre = (const float*)d_in[3];
    const float* Wl1  = (const float*)d_in[4];
    const float* bl1  = (const float*)d_in[5];
    const float* Wr1  = (const float*)d_in[6];
    const float* Wl2  = (const float*)d_in[7];
    const float* bl2  = (const float*)d_in[8];
    const float* Wr2  = (const float*)d_in[9];
    float* out = (float*)d_out;

    char* w = (char*)d_ws;
    int* counts = (int*)w;  w += (size_t)NN * 4;
    int* cursor = (int*)w;  w += (size_t)NN * 4;
    int* rowp   = (int*)w;  w += (size_t)NN * 4;
    int* bsums  = (int*)w;  w += 256;
    int* col    = (int*)w;  w += (size_t)EE * 4;
    _Float16* WAH  = (_Float16*)w; w += (size_t)256 * 128 * 2;
    _Float16* WAL  = (_Float16*)w; w += (size_t)256 * 128 * 2;
    _Float16* WBH  = (_Float16*)w; w += (size_t)256 * 128 * 2;
    _Float16* WBL  = (_Float16*)w; w += (size_t)256 * 128 * 2;
    float*    bA   = (float*)w;    w += 128 * 4;
    float*    bB   = (float*)w;    w += 128 * 4;
    _Float16* W2lH = (_Float16*)w; w += (size_t)128 * 64 * 2;
    _Float16* W2lL = (_Float16*)w; w += (size_t)128 * 64 * 2;
    _Float16* W2rH = (_Float16*)w; w += (size_t)128 * 64 * 2;
    _Float16* W2rL = (_Float16*)w; w += (size_t)128 * 64 * 2;
    _Float16* t1   = (_Float16*)w; w += (size_t)NN * 128 * 2;   // 12.8MB
    _Float16* r1   = (_Float16*)w; w += (size_t)NN * 128 * 2;
    _Float16* h1   = (_Float16*)w; w += (size_t)NN * 128 * 2;
    _Float16* t2   = (_Float16*)w; w += (size_t)NN * 64 * 2;
    _Float16* r2   = (_Float16*)w; w += (size_t)NN * 64 * 2;

    hipMemsetAsync(counts, 0, (size_t)NN * 8, stream);    // counts + cursor

    dim3 b256(256);
    dim3 gE((EE + 255) / 256);
    k_count<<<gE, b256, 0, stream>>>(ei, counts);
    k_scan_a<<<dim3(NBLK), b256, 0, stream>>>(counts, bsums);
    k_scan_b<<<dim3(1), dim3(64), 0, stream>>>(bsums);
    k_scan_c<<<dim3(NBLK), b256, 0, stream>>>(counts, bsums, rowp);
    k_scatter<<<gE, b256, 0, stream>>>(ei, rowp, cursor, col);

    k_fuse<<<dim3(257), b256, 0, stream>>>(Wpre, bpre, Wl1, Wr1,
                                           WAH, WAL, WBH, WBL, bA, bB);
    k_pack2<<<dim3(64), b256, 0, stream>>>(Wl2, Wr2, W2lH, W2lL, W2rH, W2rL);

    dim3 gP(GEMM_BLOCKS);
    k_gemm_fused<<<gP, b256, 0, stream>>>(x, WAH, WAL, WBH, WBL, bA, bB, t1, r1);
    k_aggr1<<<dim3((NN + 3) / 4), b256, 0, stream>>>(t1, r1, rowp, counts, col, bl1, h1);
    k_gemm_dual<64><<<gP, b256, 0, stream>>>(h1, W2lH, W2lL, W2rH, W2rL, t2, r2);
    k_aggr2<<<dim3((NN + 3) / 4), b256, 0, stream>>>(t2, r2, rowp, counts, col, bl2, out);
}

// Round 7
// 317.063 us; speedup vs baseline: 1.0163x; 1.0163x over previous
//
#include <hip/hip_runtime.h>

// GraphSAGE 2-layer pipeline, fp16 activations + MFMA f16 (weights hi+lo 2-term).
// linear_pre fused into conv_first:  t1 = x@(Wpre@Wl1)+b_pre@Wl1, r1 = x@(Wpre@Wr1)+b_pre@Wr1.
// GEMM waves own 16 output cols of ONE output => 64 (or 32) VGPRs of weights,
// comfortably register-resident (round-6 failure: 128 VGPRs wanted, compiler
// rematerialized weight loads per iteration -> latency-bound, VGPR_Count=88).
// N=50000, E=600000, edge_index int32.

#define NN   50000
#define EE   600000
#define NBLK 49          // ceil(NN/1024)
#define NRG64 782        // ceil(NN/64)
#define GEMM_BLOCKS 512

typedef __attribute__((ext_vector_type(8))) _Float16 h8v;
typedef __attribute__((ext_vector_type(4))) _Float16 h4v;
typedef __attribute__((ext_vector_type(2))) _Float16 h2v;
typedef __attribute__((ext_vector_type(8))) short short8v;
typedef __attribute__((ext_vector_type(4))) float f32x4;

__device__ inline h8v h8zero() {
    return __builtin_bit_cast(h8v, (short8v){0,0,0,0,0,0,0,0});
}

// ---------------- CSR build ----------------

__global__ __launch_bounds__(256) void k_count(const int* __restrict__ ei,
                                               int* __restrict__ counts) {
    int e = blockIdx.x * 256 + threadIdx.x;
    if (e < EE) atomicAdd(&counts[ei[EE + e]], 1);
}

__global__ __launch_bounds__(256) void k_scan_a(const int* __restrict__ counts,
                                                int* __restrict__ bsums) {
    int b = blockIdx.x, t = threadIdx.x;
    int idx = b * 1024 + t * 4;
    int s = 0;
#pragma unroll
    for (int j = 0; j < 4; ++j)
        if (idx + j < NN) s += counts[idx + j];
#pragma unroll
    for (int off = 32; off > 0; off >>= 1) s += __shfl_down(s, off);
    __shared__ int ls[4];
    if ((t & 63) == 0) ls[t >> 6] = s;
    __syncthreads();
    if (t == 0) bsums[b] = ls[0] + ls[1] + ls[2] + ls[3];
}

__global__ void k_scan_b(int* __restrict__ bsums) {
    int t = threadIdx.x;                       // 64 threads
    int v = (t < NBLK) ? bsums[t] : 0;
    int orig = v;
#pragma unroll
    for (int off = 1; off < 64; off <<= 1) {
        int u = __shfl_up(v, off);
        if (t >= off) v += u;
    }
    if (t < NBLK) bsums[t] = v - orig;          // exclusive
}

__global__ __launch_bounds__(256) void k_scan_c(const int* __restrict__ counts,
                                                const int* __restrict__ bsums,
                                                int* __restrict__ rowp) {
    int b = blockIdx.x, t = threadIdx.x;
    int lane = t & 63, wave = t >> 6;
    int idx = b * 1024 + t * 4;
    int c[4], s = 0;
#pragma unroll
    for (int j = 0; j < 4; ++j) {
        c[j] = (idx + j < NN) ? counts[idx + j] : 0;
        s += c[j];
    }
    int sv = s;
#pragma unroll
    for (int off = 1; off < 64; off <<= 1) {
        int u = __shfl_up(sv, off);
        if (lane >= off) sv += u;
    }
    __shared__ int lsum[4];
    if (lane == 63) lsum[wave] = sv;
    __syncthreads();
    int woff = 0;
    for (int wv = 0; wv < wave; ++wv) woff += lsum[wv];
    int base = bsums[b] + woff + (sv - s);
#pragma unroll
    for (int j = 0; j < 4; ++j) {
        if (idx + j < NN) { rowp[idx + j] = base; base += c[j]; }
    }
}

__global__ __launch_bounds__(256) void k_scatter(const int* __restrict__ ei,
                                                 const int* __restrict__ rowp,
                                                 int* __restrict__ cursor,
                                                 int* __restrict__ col) {
    int e = blockIdx.x * 256 + threadIdx.x;
    if (e < EE) {
        int d = ei[EE + e];
        int p = atomicAdd(&cursor[d], 1);
        col[rowp[d] + p] = ei[e];
    }
}

// ---------------- x: fp32 -> fp16 ----------------

__global__ __launch_bounds__(256) void k_cvt(const float* __restrict__ in,
                                             _Float16* __restrict__ outp, int n4) {
    int i = blockIdx.x * 256 + threadIdx.x;
    if (i >= n4) return;
    float4 v = ((const float4*)in)[i];
    h4v o;
    o[0] = (_Float16)v.x; o[1] = (_Float16)v.y;
    o[2] = (_Float16)v.z; o[3] = (_Float16)v.w;
    ((h4v*)outp)[i] = o;
}

// ---- prep: fused layer-1 weights (WA=Wpre@Wl1, WB=Wpre@Wr1, transposed hi/lo
// ---- fp16) + bias rows (fp32) + layer-2 packed transposed hi/lo weights.

__global__ __launch_bounds__(256) void k_prep(const float* __restrict__ Wpre,
                                              const float* __restrict__ bpre,
                                              const float* __restrict__ Wl1,
                                              const float* __restrict__ Wr1,
                                              const float* __restrict__ Wl2,
                                              const float* __restrict__ Wr2,
                                              _Float16* __restrict__ WAH,
                                              _Float16* __restrict__ WAL,
                                              _Float16* __restrict__ WBH,
                                              _Float16* __restrict__ WBL,
                                              float* __restrict__ bA,
                                              float* __restrict__ bB,
                                              _Float16* __restrict__ W2lH,
                                              _Float16* __restrict__ W2lL,
                                              _Float16* __restrict__ W2rH,
                                              _Float16* __restrict__ W2rL) {
    int idx = blockIdx.x * 256 + threadIdx.x;     // 321*256 = 82176 exact
    if (idx < 65792) {                            // 2*257*128: layer-1 fuse
        int which = idx / (257 * 128);
        int rem = idx - which * 257 * 128;
        int i = rem >> 7, j = rem & 127;
        const float* W = which ? Wr1 : Wl1;
        float s = 0.f;
        if (i < 256) {
#pragma unroll 4
            for (int k = 0; k < 128; ++k) s += Wpre[i * 128 + k] * W[k * 128 + j];
            _Float16 h = (_Float16)s;
            _Float16 l = (_Float16)(s - (float)h);
            if (which) { WBH[j * 256 + i] = h; WBL[j * 256 + i] = l; }
            else       { WAH[j * 256 + i] = h; WAL[j * 256 + i] = l; }
        } else {
#pragma unroll 4
            for (int k = 0; k < 128; ++k) s += bpre[k] * W[k * 128 + j];
            if (which) bB[j] = s; else bA[j] = s;
        }
    } else {                                      // 2*8192: layer-2 pack
        int idx2 = idx - 65792;
        int which = idx2 >> 13;
        int rem = idx2 & 8191;
        int k = rem >> 6, m = rem & 63;
        float w = (which ? Wr2 : Wl2)[rem];
        _Float16 h = (_Float16)w;
        _Float16 l = (_Float16)(w - (float)h);
        if (which) { W2rH[m * 128 + k] = h; W2rL[m * 128 + k] = l; }
        else       { W2lH[m * 128 + k] = h; W2lL[m * 128 + k] = l; }
    }
}

// ---- fused dual GEMM: t1 = xh@WA + bA, r1 = xh@WB + bB  (K=256) -------------
// 16 slices = {t1,r1} x 8 col-slices of 16. Wave holds ONE slice's weights
// (wh[8]+wl[8] = 64 VGPR). 64-row groups (4 independent acc chains). The 4
// waves of a block share the row-group (A L2 reuse).

__global__ __launch_bounds__(256, 2) void k_gemm_fused(
        const _Float16* __restrict__ xh,
        const _Float16* __restrict__ WAH, const _Float16* __restrict__ WAL,
        const _Float16* __restrict__ WBH, const _Float16* __restrict__ WBL,
        const float* __restrict__ bA, const float* __restrict__ bB,
        _Float16* __restrict__ t1, _Float16* __restrict__ r1) {
    const int wave = threadIdx.x >> 6, lane = threadIdx.x & 63;
    const int r = lane & 15, kb = lane >> 4;
    const int s = ((blockIdx.x & 3) << 2) + wave;   // 0..15
    const int sel = s >> 3;                         // 0 -> t1, 1 -> r1
    const int col = ((s & 7) << 4) + r;
    const _Float16* __restrict__ WH = sel ? WBH : WAH;
    const _Float16* __restrict__ WL = sel ? WBL : WAL;
    _Float16* __restrict__ dst = sel ? r1 : t1;
    const float bias = (sel ? bB : bA)[col];

    h8v wh[8], wl[8];
#pragma unroll
    for (int k = 0; k < 8; ++k) {
        size_t off = (size_t)col * 256 + k * 32 + kb * 8;
        wh[k] = *(const h8v*)&WH[off];
        wl[k] = *(const h8v*)&WL[off];
    }

    for (int rg = blockIdx.x >> 2; rg < NRG64; rg += GEMM_BLOCKS / 4) {
        const int row0 = rg << 6;
        f32x4 acc[4];
#pragma unroll
        for (int a = 0; a < 4; ++a) acc[a] = (f32x4){0.f, 0.f, 0.f, 0.f};

#pragma unroll
        for (int k = 0; k < 8; ++k) {
            h8v a[4];
#pragma unroll
            for (int rt = 0; rt < 4; ++rt) {
                int rr = row0 + rt * 16;            // tile-uniform validity
                a[rt] = (rr < NN)
                    ? *(const h8v*)&xh[(size_t)(rr + r) * 256 + k * 32 + kb * 8]
                    : h8zero();
            }
#pragma unroll
            for (int rt = 0; rt < 4; ++rt) {
                acc[rt] = __builtin_amdgcn_mfma_f32_16x16x32_f16(a[rt], wh[k], acc[rt], 0, 0, 0);
                acc[rt] = __builtin_amdgcn_mfma_f32_16x16x32_f16(a[rt], wl[k], acc[rt], 0, 0, 0);
            }
        }
#pragma unroll
        for (int rt = 0; rt < 4; ++rt) {
            int rr = row0 + rt * 16;
            if (rr >= NN) continue;
            int rbase = rr + kb * 4;                // C: row = 4*(lane>>4)+reg
#pragma unroll
            for (int j = 0; j < 4; ++j)
                dst[(size_t)(rbase + j) * 128 + col] = (_Float16)(acc[rt][j] + bias);
        }
    }
}

// ---- layer-2 dual GEMM: t2 = h1@Wl2, r2 = h1@Wr2  (K=128, M=64) -------------
// 8 slices = {t2,r2} x 4 col-slices of 16; weights 32 VGPR; 64-row groups.

__global__ __launch_bounds__(256, 2) void k_gemm_dual2(
        const _Float16* __restrict__ A,
        const _Float16* __restrict__ W1H, const _Float16* __restrict__ W1L,
        const _Float16* __restrict__ W2H, const _Float16* __restrict__ W2L,
        _Float16* __restrict__ T, _Float16* __restrict__ R) {
    const int wave = threadIdx.x >> 6, lane = threadIdx.x & 63;
    const int r = lane & 15, kb = lane >> 4;
    const int s = ((blockIdx.x & 1) << 2) + wave;   // 0..7
    const int sel = s >> 2;                         // 0 -> T, 1 -> R
    const int col = ((s & 3) << 4) + r;
    const _Float16* __restrict__ WH = sel ? W2H : W1H;
    const _Float16* __restrict__ WL = sel ? W2L : W1L;
    _Float16* __restrict__ dst = sel ? R : T;

    h8v wh[4], wl[4];
#pragma unroll
    for (int k = 0; k < 4; ++k) {
        size_t off = (size_t)col * 128 + k * 32 + kb * 8;
        wh[k] = *(const h8v*)&WH[off];
        wl[k] = *(const h8v*)&WL[off];
    }

    for (int rg = blockIdx.x >> 1; rg < NRG64; rg += GEMM_BLOCKS / 2) {
        const int row0 = rg << 6;
        f32x4 acc[4];
#pragma unroll
        for (int a = 0; a < 4; ++a) acc[a] = (f32x4){0.f, 0.f, 0.f, 0.f};

#pragma unroll
        for (int k = 0; k < 4; ++k) {
            h8v a[4];
#pragma unroll
            for (int rt = 0; rt < 4; ++rt) {
                int rr = row0 + rt * 16;
                a[rt] = (rr < NN)
                    ? *(const h8v*)&A[(size_t)(rr + r) * 128 + k * 32 + kb * 8]
                    : h8zero();
            }
#pragma unroll
            for (int rt = 0; rt < 4; ++rt) {
                acc[rt] = __builtin_amdgcn_mfma_f32_16x16x32_f16(a[rt], wh[k], acc[rt], 0, 0, 0);
                acc[rt] = __builtin_amdgcn_mfma_f32_16x16x32_f16(a[rt], wl[k], acc[rt], 0, 0, 0);
            }
        }
#pragma unroll
        for (int rt = 0; rt < 4; ++rt) {
            int rr = row0 + rt * 16;
            if (rr >= NN) continue;
            int rbase = rr + kb * 4;
#pragma unroll
            for (int j = 0; j < 4; ++j)
                dst[(size_t)(rbase + j) * 64 + col] = (_Float16)acc[rt][j];
        }
    }
}

// ------- Aggregation 1: h1 = fp16(relu(mean(t1[src]) + bl1 + r1)) -------------
// one wave per node; two 32-lane halves, h4v (8B) loads, 2 neighbors/step.

__global__ __launch_bounds__(256) void k_aggr1(const _Float16* __restrict__ t1,
                                               const _Float16* __restrict__ r1,
                                               const int* __restrict__ rowp,
                                               const int* __restrict__ counts,
                                               const int* __restrict__ col,
                                               const float* __restrict__ bl1,
                                               _Float16* __restrict__ h1) {
    int node = blockIdx.x * 4 + (threadIdx.x >> 6);
    int lane = threadIdx.x & 63;
    if (node >= NN) return;
    int half = lane >> 5, sl = lane & 31;
    int e0 = rowp[node], cnt = counts[node];
    float a0 = 0.f, a1 = 0.f, a2 = 0.f, a3 = 0.f;
    const h4v* T = (const h4v*)t1;                 // 32 h4v per row
    for (int base = 0; base < cnt; base += 64) {
        int m = cnt - base; if (m > 64) m = 64;
        int myS = (base + lane < cnt) ? col[e0 + base + lane] : 0;
        int i = 0;
        for (; i + 8 <= m; i += 8) {
            int s0 = __shfl(myS, i + 0 + half), s1 = __shfl(myS, i + 2 + half);
            int s2 = __shfl(myS, i + 4 + half), s3 = __shfl(myS, i + 6 + half);
            h4v v0 = T[(size_t)s0 * 32 + sl], v1 = T[(size_t)s1 * 32 + sl];
            h4v v2 = T[(size_t)s2 * 32 + sl], v3 = T[(size_t)s3 * 32 + sl];
            a0 += (float)v0[0] + (float)v1[0] + (float)v2[0] + (float)v3[0];
            a1 += (float)v0[1] + (float)v1[1] + (float)v2[1] + (float)v3[1];
            a2 += (float)v0[2] + (float)v1[2] + (float)v2[2] + (float)v3[2];
            a3 += (float)v0[3] + (float)v1[3] + (float)v2[3] + (float)v3[3];
        }
        for (; i < m; i += 2) {
            if (i + half < m) {
                int s = __shfl(myS, i + half);
                h4v v = T[(size_t)s * 32 + sl];
                a0 += (float)v[0]; a1 += (float)v[1];
                a2 += (float)v[2]; a3 += (float)v[3];
            }
        }
    }
    a0 += __shfl_xor(a0, 32); a1 += __shfl_xor(a1, 32);
    a2 += __shfl_xor(a2, 32); a3 += __shfl_xor(a3, 32);
    float di = (cnt > 0) ? 1.0f / (float)cnt : 0.0f;
    h4v rr = ((const h4v*)r1)[(size_t)node * 32 + sl];
    float4 bb = ((const float4*)bl1)[sl];
    if (half == 0) {
        h4v h;
        h[0] = (_Float16)fmaxf(fmaf(a0, di, bb.x + (float)rr[0]), 0.0f);
        h[1] = (_Float16)fmaxf(fmaf(a1, di, bb.y + (float)rr[1]), 0.0f);
        h[2] = (_Float16)fmaxf(fmaf(a2, di, bb.z + (float)rr[2]), 0.0f);
        h[3] = (_Float16)fmaxf(fmaf(a3, di, bb.w + (float)rr[3]), 0.0f);
        ((h4v*)h1)[(size_t)node * 32 + sl] = h;
    }
}

// ------- Aggregation 2 + L2 normalize -----------------------------------------

__global__ __launch_bounds__(256) void k_aggr2(const _Float16* __restrict__ t2,
                                               const _Float16* __restrict__ r2,
                                               const int* __restrict__ rowp,
                                               const int* __restrict__ counts,
                                               const int* __restrict__ col,
                                               const float* __restrict__ bl2,
                                               float* __restrict__ out) {
    int node = blockIdx.x * 4 + (threadIdx.x >> 6);
    int lane = threadIdx.x & 63;
    if (node >= NN) return;
    int half = lane >> 5, sl = lane & 31;
    int e0 = rowp[node], cnt = counts[node];
    float ax = 0.f, ay = 0.f;
    const h2v* T = (const h2v*)t2;
    for (int base = 0; base < cnt; base += 64) {
        int m = cnt - base; if (m > 64) m = 64;
        int myS = (base + lane < cnt) ? col[e0 + base + lane] : 0;
        int i = 0;
        for (; i + 8 <= m; i += 8) {
            int s0 = __shfl(myS, i + 0 + half), s1 = __shfl(myS, i + 2 + half);
            int s2 = __shfl(myS, i + 4 + half), s3 = __shfl(myS, i + 6 + half);
            h2v v0 = T[(size_t)s0 * 32 + sl], v1 = T[(size_t)s1 * 32 + sl];
            h2v v2 = T[(size_t)s2 * 32 + sl], v3 = T[(size_t)s3 * 32 + sl];
            ax += (float)v0[0] + (float)v1[0] + (float)v2[0] + (float)v3[0];
            ay += (float)v0[1] + (float)v1[1] + (float)v2[1] + (float)v3[1];
        }
        for (; i < m; i += 2) {
            if (i + half < m) {
                int s = __shfl(myS, i + half);
                h2v v = T[(size_t)s * 32 + sl];
                ax += (float)v[0]; ay += (float)v[1];
            }
        }
    }
    ax += __shfl_xor(ax, 32);
    ay += __shfl_xor(ay, 32);
    float di = (cnt > 0) ? 1.0f / (float)cnt : 0.0f;
    h2v rr = ((const h2v*)r2)[(size_t)node * 32 + sl];
    float2 bb = ((const float2*)bl2)[sl];
    float v0 = fmaf(ax, di, bb.x + (float)rr[0]);
    float v1 = fmaf(ay, di, bb.y + (float)rr[1]);
    float ss = v0 * v0 + v1 * v1;
#pragma unroll
    for (int off = 16; off > 0; off >>= 1) ss += __shfl_xor(ss, off);
    float inv = 1.0f / fmaxf(sqrtf(ss), 1e-12f);
    if (half == 0)
        ((float2*)out)[(size_t)node * 32 + sl] = make_float2(v0 * inv, v1 * inv);
}

// ---------------- launch ----------------

extern "C" void kernel_launch(void* const* d_in, const int* in_sizes, int n_in,
                              void* d_out, int out_size, void* d_ws, size_t ws_size,
                              hipStream_t stream) {
    const float* x    = (const float*)d_in[0];
    const int*   ei   = (const int*)d_in[1];
    const float* Wpre = (const float*)d_in[2];
    const float* bpre = (const float*)d_in[3];
    const float* Wl1  = (const float*)d_in[4];
    const float* bl1  = (const float*)d_in[5];
    const float* Wr1  = (const float*)d_in[6];
    const float* Wl2  = (const float*)d_in[7];
    const float* bl2  = (const float*)d_in[8];
    const float* Wr2  = (const float*)d_in[9];
    float* out = (float*)d_out;

    char* w = (char*)d_ws;
    int* counts = (int*)w;  w += (size_t)NN * 4;
    int* cursor = (int*)w;  w += (size_t)NN * 4;
    int* rowp   = (int*)w;  w += (size_t)NN * 4;
    int* bsums  = (int*)w;  w += 256;
    int* col    = (int*)w;  w += (size_t)EE * 4;
    _Float16* WAH  = (_Float16*)w; w += (size_t)256 * 128 * 2;
    _Float16* WAL  = (_Float16*)w; w += (size_t)256 * 128 * 2;
    _Float16* WBH  = (_Float16*)w; w += (size_t)256 * 128 * 2;
    _Float16* WBL  = (_Float16*)w; w += (size_t)256 * 128 * 2;
    float*    bA   = (float*)w;    w += 128 * 4;
    float*    bB   = (float*)w;    w += 128 * 4;
    _Float16* W2lH = (_Float16*)w; w += (size_t)128 * 64 * 2;
    _Float16* W2lL = (_Float16*)w; w += (size_t)128 * 64 * 2;
    _Float16* W2rH = (_Float16*)w; w += (size_t)128 * 64 * 2;
    _Float16* W2rL = (_Float16*)w; w += (size_t)128 * 64 * 2;
    _Float16* xh   = (_Float16*)w; w += (size_t)NN * 256 * 2;   // 25.6MB
    _Float16* t1   = (_Float16*)w; w += (size_t)NN * 128 * 2;   // 12.8MB
    _Float16* r1   = (_Float16*)w; w += (size_t)NN * 128 * 2;
    _Float16* h1   = (_Float16*)w; w += (size_t)NN * 128 * 2;
    _Float16* t2   = (_Float16*)w; w += (size_t)NN * 64 * 2;
    _Float16* r2   = (_Float16*)w; w += (size_t)NN * 64 * 2;

    hipMemsetAsync(counts, 0, (size_t)NN * 8, stream);    // counts + cursor

    dim3 b256(256);
    dim3 gE((EE + 255) / 256);
    k_count<<<gE, b256, 0, stream>>>(ei, counts);
    k_scan_a<<<dim3(NBLK), b256, 0, stream>>>(counts, bsums);
    k_scan_b<<<dim3(1), dim3(64), 0, stream>>>(bsums);
    k_scan_c<<<dim3(NBLK), b256, 0, stream>>>(counts, bsums, rowp);
    k_scatter<<<gE, b256, 0, stream>>>(ei, rowp, cursor, col);

    k_cvt<<<dim3(NN * 256 / 4 / 256), b256, 0, stream>>>(x, xh, NN * 256 / 4);
    k_prep<<<dim3(321), b256, 0, stream>>>(Wpre, bpre, Wl1, Wr1, Wl2, Wr2,
                                           WAH, WAL, WBH, WBL, bA, bB,
                                           W2lH, W2lL, W2rH, W2rL);

    dim3 gP(GEMM_BLOCKS);
    k_gemm_fused<<<gP, b256, 0, stream>>>(xh, WAH, WAL, WBH, WBL, bA, bB, t1, r1);
    k_aggr1<<<dim3((NN + 3) / 4), b256, 0, stream>>>(t1, r1, rowp, counts, col, bl1, h1);
    k_gemm_dual2<<<gP, b256, 0, stream>>>(h1, W2lH, W2lL, W2rH, W2rL, t2, r2);
    k_aggr2<<<dim3((NN + 3) / 4), b256, 0, stream>>>(t2, r2, rowp, counts, col, bl2, out);
}